// Round 14
// baseline (582.007 us; speedup 1.0000x reference)
//
#include <hip/hip_runtime.h>
#include <hip/hip_bf16.h>
#include <cstdint>

#define IN_C 256

typedef __attribute__((ext_vector_type(8))) short bf16x8;
typedef __attribute__((ext_vector_type(8))) short s16x8;
typedef __attribute__((ext_vector_type(4))) short s16x4;
typedef __attribute__((ext_vector_type(8))) unsigned short u16x8;
typedef __attribute__((ext_vector_type(4))) float f32x4;

#define FIXED_SCALE 33554432.0f          // 2^25
#define FIXED_INV   (1.0f / 33554432.0f)
#define DEG_MASK    ((1ULL << 40) - 1)

// ---- bf16 split helpers (RNE) ----
__device__ inline unsigned short f2bf(float f) {
    union { float f; unsigned int u; } v; v.f = f;
    unsigned int r = (v.u + 0x7fffu + ((v.u >> 16) & 1u)) >> 16;
    return (unsigned short)r;
}
__device__ inline float bf2f(unsigned short b) {
    union { unsigned int u; float f; } v; v.u = ((unsigned int)b) << 16;
    return v.f;
}
// returns .x = hi bf16 bits, .y = lo bf16 bits
__device__ inline short2 split1(float f) {
    unsigned short hb = f2bf(f);
    unsigned short lb = f2bf(f - bf2f(hb));
    return make_short2((short)hb, (short)lb);
}

// ---------------- per-edge: ONE packed u64 atomic = deg (fixed-point) + cnt + rank ----
__global__ void deg_count_kernel(const int* __restrict__ ei, const float* __restrict__ w,
                                 unsigned long long* __restrict__ packed,
                                 unsigned short* __restrict__ rank, int E) {
    int e = blockIdx.x * blockDim.x + threadIdx.x;
    if (e >= E) return;
    int dst = ei[E + e];
    unsigned int fx = __float2uint_rn(w[e] * FIXED_SCALE);
    unsigned long long inc = (1ULL << 40) | (unsigned long long)fx;
    unsigned long long old = atomicAdd(&packed[dst], inc);
    rank[e] = (unsigned short)(old >> 40);
}

// ---------------- exclusive scan of cnt -> row_ptr (3-kernel); scan1 also dinv ----------------
#define SCAN_B 256
__global__ void scan1_kernel(const unsigned long long* __restrict__ packed,
                             int* __restrict__ rp, int* __restrict__ bsum,
                             float* __restrict__ dinv, int N) {
    __shared__ int s[SCAN_B];
    int tid = threadIdx.x;
    int i = blockIdx.x * SCAN_B + tid;
    int v = 0;
    if (i < N) {
        unsigned long long pk = packed[i];
        v = (int)(pk >> 40);
        float deg = (float)(pk & DEG_MASK) * FIXED_INV;
        dinv[i] = rsqrtf(deg + 1.0f);         // +1 = self loop weight
    }
    s[tid] = v;
    __syncthreads();
    for (int off = 1; off < SCAN_B; off <<= 1) {
        int t = (tid >= off) ? s[tid - off] : 0;
        __syncthreads();
        s[tid] += t;
        __syncthreads();
    }
    if (i < N) rp[i] = s[tid] - v;            // exclusive within block
    if (tid == SCAN_B - 1) bsum[blockIdx.x] = s[tid];
}

__global__ void scan2_kernel(int* __restrict__ bsum, int* __restrict__ boff, int nb) {
    __shared__ int s[SCAN_B];
    int tid = threadIdx.x;
    int v = (tid < nb) ? bsum[tid] : 0;
    s[tid] = v;
    __syncthreads();
    for (int off = 1; off < SCAN_B; off <<= 1) {
        int t = (tid >= off) ? s[tid - off] : 0;
        __syncthreads();
        s[tid] += t;
        __syncthreads();
    }
    if (tid < nb) boff[tid] = s[tid] - v;     // exclusive across blocks
}

__global__ void scan3_kernel(int* __restrict__ rp, const int* __restrict__ boff,
                             int N, int E) {
    int i = blockIdx.x * blockDim.x + threadIdx.x;
    if (i < N) rp[i] = rp[i] + boff[i >> 8];
    if (i == 0) rp[N] = E;
}

// ---------------- CSR fill, ATOMIC-FREE: pos = rp[dst] + rank[e] ----------------
__global__ void fill_kernel(const int* __restrict__ ei, const float* __restrict__ w,
                            const float* __restrict__ dinv,
                            const int* __restrict__ rp,
                            const unsigned short* __restrict__ rank,
                            int2* __restrict__ cv, int E) {
    int e = blockIdx.x * blockDim.x + threadIdx.x;
    if (e >= E) return;
    int src = ei[e];
    int dst = ei[E + e];
    int pos = rp[dst] + (int)rank[e];
    // defensive clamp: never allow a wild store outside [0,E)
    if ((unsigned)pos < (unsigned)E) {
        float v = dinv[src] * w[e] * dinv[dst];
        cv[pos] = make_int2(src, __float_as_int(v));
    }
}

// ---------------- prep: W1/W2 transpose+split AND x split, one launch ----------------
__global__ void prep_kernel(const float* __restrict__ W1, const float* __restrict__ W2,
                            const float* __restrict__ x,
                            unsigned short* __restrict__ w1t_hi, unsigned short* __restrict__ w1t_lo,
                            unsigned short* __restrict__ w2t_hi, unsigned short* __restrict__ w2t_lo,
                            unsigned short* __restrict__ x_hi, unsigned short* __restrict__ x_lo,
                            int nx4) {
    int b = blockIdx.x;
    if (b < 512) {
        const float* W = (b < 256) ? W1 : W2;
        unsigned short* hi = (b < 256) ? w1t_hi : w2t_hi;
        unsigned short* lo = (b < 256) ? w1t_lo : w2t_lo;
        int n = b & 255;       // col of W
        int k = threadIdx.x;   // row of W
        float v = W[(size_t)k * 256 + n];
        short2 s = split1(v);
        hi[(size_t)n * 256 + k] = (unsigned short)s.x;
        lo[(size_t)n * 256 + k] = (unsigned short)s.y;
    } else {
        int i = (b - 512) * 256 + threadIdx.x;   // float4 index
        if (i < nx4) {
            float4 v = ((const float4*)x)[i];
            short2 sx = split1(v.x), sy = split1(v.y), sz = split1(v.z), sw = split1(v.w);
            s16x4 hv, lv;
            hv.x = sx.x; hv.y = sy.x; hv.z = sz.x; hv.w = sw.x;
            lv.x = sx.y; lv.y = sy.y; lv.z = sz.y; lv.w = sw.y;
            *(s16x4*)(x_hi + (size_t)i * 4) = hv;
            *(s16x4*)(x_lo + (size_t)i * 4) = lv;
        }
    }
}

// ---------------- split-bf16 MFMA GEMM ----------------
// C16[N][256] (plain bf16) = A[N][256] @ B[256][256] in ~fp32 precision via 3x bf16 MFMA.
__global__ __launch_bounds__(256) void gemm_split_kernel(
    const unsigned short* __restrict__ Ahg,
    const unsigned short* __restrict__ Alg,
    const unsigned short* __restrict__ Bth,   // Wt_hi [n][k]
    const unsigned short* __restrict__ Btl,   // Wt_lo [n][k]
    unsigned short* __restrict__ C16, int Nrows)
{
    __shared__ __align__(16) short Ah[128 * 64];
    __shared__ __align__(16) short Al[128 * 64];
    __shared__ __align__(16) short Bh[128 * 64];
    __shared__ __align__(16) short Bl[128 * 64];

    const int t    = threadIdx.x;
    const int lane = t & 63;
    const int w    = t >> 6;
    const int r0   = blockIdx.x * 128;
    const int cb0  = blockIdx.y * 128;
    const int fr   = lane & 15;          // frag row (A: m-row / B: n-col)
    const int fk   = (lane >> 4) * 8;    // frag k offset
    const int wm   = w * 32;             // wave's m-band

    f32x4 acc[2][8] = {};

    for (int k0 = 0; k0 < 256; k0 += 64) {
        __syncthreads();
        // ---- stage B tile [128 n][64 k] (hi+lo) ----
#pragma unroll
        for (int c = 0; c < 4; ++c) {
            int i = c * 256 + t;
            int row = i >> 3, seg = i & 7;
            size_t g = (size_t)(cb0 + row) * 256 + k0 + seg * 8;
            *(s16x8*)&Bh[row * 64 + seg * 8] = *(const s16x8*)(Bth + g);
            *(s16x8*)&Bl[row * 64 + seg * 8] = *(const s16x8*)(Btl + g);
        }
        // ---- stage A tile [128 m][64 k] (hi+lo) ----
#pragma unroll
        for (int c = 0; c < 4; ++c) {
            int i = c * 256 + t;
            int row = i >> 3, seg = i & 7;
            int gr = r0 + row; if (gr > Nrows - 1) gr = Nrows - 1;
            size_t g = (size_t)gr * 256 + k0 + seg * 8;
            *(s16x8*)&Ah[row * 64 + seg * 8] = *(const s16x8*)(Ahg + g);
            *(s16x8*)&Al[row * 64 + seg * 8] = *(const s16x8*)(Alg + g);
        }
        __syncthreads();
        // ---- compute: 2 k-steps of 32, 2m x 8n frags, 3 MFMA each ----
#pragma unroll
        for (int ks = 0; ks < 2; ++ks) {
            int ko = ks * 32 + fk;
            bf16x8 ah[2], al[2];
#pragma unroll
            for (int mi = 0; mi < 2; ++mi) {
                ah[mi] = *(const bf16x8*)&Ah[(wm + mi * 16 + fr) * 64 + ko];
                al[mi] = *(const bf16x8*)&Al[(wm + mi * 16 + fr) * 64 + ko];
            }
#pragma unroll
            for (int n = 0; n < 8; ++n) {
                bf16x8 bh = *(const bf16x8*)&Bh[(n * 16 + fr) * 64 + ko];
                bf16x8 bl = *(const bf16x8*)&Bl[(n * 16 + fr) * 64 + ko];
#pragma unroll
                for (int mi = 0; mi < 2; ++mi) {
                    acc[mi][n] = __builtin_amdgcn_mfma_f32_16x16x32_bf16(ah[mi], bh, acc[mi][n], 0, 0, 0);
                    acc[mi][n] = __builtin_amdgcn_mfma_f32_16x16x32_bf16(ah[mi], bl, acc[mi][n], 0, 0, 0);
                    acc[mi][n] = __builtin_amdgcn_mfma_f32_16x16x32_bf16(al[mi], bh, acc[mi][n], 0, 0, 0);
                }
            }
        }
    }
    // ---- epilogue: C/D layout col=lane&15, row=(lane>>4)*4+reg; store plain bf16 ----
    const int rb = (lane >> 4) * 4;
#pragma unroll
    for (int mi = 0; mi < 2; ++mi) {
#pragma unroll
        for (int n = 0; n < 8; ++n) {
            int col = cb0 + n * 16 + fr;
#pragma unroll
            for (int r = 0; r < 4; ++r) {
                int row = r0 + wm + mi * 16 + rb + r;
                if (row < Nrows) C16[(size_t)row * 256 + col] = f2bf(acc[mi][n][r]);
            }
        }
    }
}

// ---- 8-channel bf16 FMA helper ----
__device__ inline void fma8(float* acc, u16x8 g, float v) {
#pragma unroll
    for (int c = 0; c < 8; ++c) acc[c] = fmaf(v, bf2f(g[c]), acc[c]);
}

// ---------------- CHANNEL-PHASED CSR aggregation ----------------
// blockIdx.y = phase (0..7), 32 channels/phase: per-phase gather working set
// = N*64B = 3.2MB < 4MB/XCD L2 -> gathers become L2 hits after compulsory fill.
// Quarter-wave (4 lanes x 16B = 64B slice) per dst; unroll-8 edge loop keeps
// 8 dwordx4 gathers in flight per lane (proven load shape; 8B loads are 6.7x
// slower — R6/R7). MODE 0 is bit-identical to the unphased version (same
// per-channel fp32 chain, same edge order).
// MODE 0: relu + bf16 hi/lo split.  MODE 1: relu + head partial -> atomicAdd.
template<int MODE>
__global__ __launch_bounds__(256) void agg_kernel(const unsigned short* __restrict__ h16,
                                                  const int* __restrict__ rp,
                                                  const int2* __restrict__ cv,
                                                  const float* __restrict__ dinv,
                                                  const float* __restrict__ bias,
                                                  unsigned short* __restrict__ out_hi,
                                                  unsigned short* __restrict__ out_lo,
                                                  const float* __restrict__ Wf,
                                                  const float* __restrict__ bf,
                                                  float* __restrict__ out,
                                                  int N) {
    int q  = threadIdx.x >> 2;               // quarter id 0..63
    int ql = threadIdx.x & 3;                // lane within quarter
    int d  = blockIdx.x * 64 + q;
    if (d >= N) return;
    int co = blockIdx.y * 32 + ql * 8;       // this lane's channel offset

    float di = dinv[d];
    float selfm = di * di;                   // self loop, weight 1
    u16x8 sv = *(const u16x8*)(h16 + (size_t)d * 256 + co);
    float acc[8];
#pragma unroll
    for (int c = 0; c < 8; ++c) acc[c] = selfm * bf2f(sv[c]);

    int s = rp[d], e = rp[d + 1];
    for (int j = s; j < e; j += 8) {
        int   ec[8]; float ev[8];
#pragma unroll
        for (int i = 0; i < 8; ++i) {
            int idx = j + i;
            int2 c = cv[idx < e ? idx : e - 1];
            ec[i] = c.x;
            ev[i] = (idx < e) ? __int_as_float(c.y) : 0.0f;
        }
        u16x8 g0 = *(const u16x8*)(h16 + (size_t)ec[0] * 256 + co);
        u16x8 g1 = *(const u16x8*)(h16 + (size_t)ec[1] * 256 + co);
        u16x8 g2 = *(const u16x8*)(h16 + (size_t)ec[2] * 256 + co);
        u16x8 g3 = *(const u16x8*)(h16 + (size_t)ec[3] * 256 + co);
        u16x8 g4 = *(const u16x8*)(h16 + (size_t)ec[4] * 256 + co);
        u16x8 g5 = *(const u16x8*)(h16 + (size_t)ec[5] * 256 + co);
        u16x8 g6 = *(const u16x8*)(h16 + (size_t)ec[6] * 256 + co);
        u16x8 g7 = *(const u16x8*)(h16 + (size_t)ec[7] * 256 + co);
        fma8(acc, g0, ev[0]);
        fma8(acc, g1, ev[1]);
        fma8(acc, g2, ev[2]);
        fma8(acc, g3, ev[3]);
        fma8(acc, g4, ev[4]);
        fma8(acc, g5, ev[5]);
        fma8(acc, g6, ev[6]);
        fma8(acc, g7, ev[7]);
    }

    float4 b0 = *(const float4*)(bias + co);
    float4 b1 = *(const float4*)(bias + co + 4);
    acc[0] = fmaxf(acc[0] + b0.x, 0.0f);
    acc[1] = fmaxf(acc[1] + b0.y, 0.0f);
    acc[2] = fmaxf(acc[2] + b0.z, 0.0f);
    acc[3] = fmaxf(acc[3] + b0.w, 0.0f);
    acc[4] = fmaxf(acc[4] + b1.x, 0.0f);
    acc[5] = fmaxf(acc[5] + b1.y, 0.0f);
    acc[6] = fmaxf(acc[6] + b1.z, 0.0f);
    acc[7] = fmaxf(acc[7] + b1.w, 0.0f);

    if constexpr (MODE == 0) {
        u16x8 hi, lo;
#pragma unroll
        for (int c = 0; c < 8; ++c) {
            hi[c] = f2bf(acc[c]);
            lo[c] = f2bf(acc[c] - bf2f(hi[c]));
        }
        *(u16x8*)(out_hi + (size_t)d * 256 + co) = hi;
        *(u16x8*)(out_lo + (size_t)d * 256 + co) = lo;
    } else {
        float4 wf0 = *(const float4*)(Wf + co);
        float4 wf1 = *(const float4*)(Wf + co + 4);
        float sdot = acc[0] * wf0.x + acc[1] * wf0.y + acc[2] * wf0.z + acc[3] * wf0.w
                   + acc[4] * wf1.x + acc[5] * wf1.y + acc[6] * wf1.z + acc[7] * wf1.w;
        sdot += __shfl_xor(sdot, 1);
        sdot += __shfl_xor(sdot, 2);
        if (ql == 0) {
            if (blockIdx.y == 0) sdot += bf[0];   // bias added exactly once
            atomicAdd(&out[d], sdot);
        }
    }
}

// ---------------- host launch ----------------
extern "C" void kernel_launch(void* const* d_in, const int* in_sizes, int n_in,
                              void* d_out, int out_size, void* d_ws, size_t ws_size,
                              hipStream_t stream) {
    const float* x  = (const float*)d_in[0];
    const int*   ei = (const int*)d_in[1];
    const float* w  = (const float*)d_in[2];
    const float* W1 = (const float*)d_in[3];
    const float* b1 = (const float*)d_in[4];
    const float* W2 = (const float*)d_in[5];
    const float* b2 = (const float*)d_in[6];
    const float* Wf = (const float*)d_in[7];
    const float* bf = (const float*)d_in[8];
    float* out = (float*)d_out;

    const int N = in_sizes[0] / IN_C;
    const int E = in_sizes[2];

    // workspace layout (256B aligned)
    auto align256 = [](size_t v) { return (v + 255) & ~(size_t)255; };
    char* p = (char*)d_ws;
    unsigned long long* packed = (unsigned long long*)p; p += align256((size_t)N * 8);
    float* dinv   = (float*)p; p += align256((size_t)N * 4);
    int*   rp     = (int*)p;   p += align256(((size_t)N + 1) * 4);
    int*   bsum   = (int*)p;   p += align256(SCAN_B * 4);
    int*   boff   = (int*)p;   p += align256(SCAN_B * 4);
    unsigned short* rank = (unsigned short*)p; p += align256((size_t)E * 2);
    int2*  cv     = (int2*)p;  p += align256((size_t)E * 8);
    unsigned short* w1t_hi = (unsigned short*)p; p += align256((size_t)256 * 256 * 2);
    unsigned short* w1t_lo = (unsigned short*)p; p += align256((size_t)256 * 256 * 2);
    unsigned short* w2t_hi = (unsigned short*)p; p += align256((size_t)256 * 256 * 2);
    unsigned short* w2t_lo = (unsigned short*)p; p += align256((size_t)256 * 256 * 2);
    unsigned short* hbuf  = (unsigned short*)p; p += align256((size_t)N * 256 * 2);  // plain bf16 GEMM out
    // xa_hi/xa_lo: x pre-split (read by GEMM1), then REUSED by agg1 as a_hi/a_lo
    unsigned short* xa_hi = (unsigned short*)p; p += align256((size_t)N * 256 * 2);
    unsigned short* xa_lo = (unsigned short*)p; p += align256((size_t)N * 256 * 2);
    (void)ws_size; (void)n_in; (void)out_size;

    const int nb_edges = (E + 255) / 256;
    const int nb_nodes = (N + 255) / 256;
    const int nb_scan  = (N + SCAN_B - 1) / SCAN_B;
    const int nx4      = N * 256 / 4;

    // zero packed deg/cnt accumulators + output (head accumulates via atomics)
    hipMemsetAsync(packed, 0, (size_t)N * 8, stream);
    hipMemsetAsync(out, 0, (size_t)N * 4, stream);

    // graph normalization + CSR build (single atomic pass; fill is atomic-free)
    deg_count_kernel<<<nb_edges, 256, 0, stream>>>(ei, w, packed, rank, E);
    scan1_kernel<<<nb_scan, SCAN_B, 0, stream>>>(packed, rp, bsum, dinv, N);
    scan2_kernel<<<1, SCAN_B, 0, stream>>>(bsum, boff, nb_scan);
    scan3_kernel<<<nb_nodes, 256, 0, stream>>>(rp, boff, N, E);
    fill_kernel<<<nb_edges, 256, 0, stream>>>(ei, w, dinv, rp, rank, cv, E);

    // prep: W1/W2 transpose+split and x split, one launch
    prep_kernel<<<512 + (nx4 + 255) / 256, 256, 0, stream>>>(
        W1, W2, x, w1t_hi, w1t_lo, w2t_hi, w2t_lo, xa_hi, xa_lo, nx4);

    dim3 ggrid((N + 127) / 128, 2);
    dim3 agrid((N + 63) / 64, 8);        // y = channel phase (slow-varying)

    // layer 1: GEMM (pre-split x) -> bf16 h -> agg (writes bf16 hi/lo into xa_*)
    gemm_split_kernel<<<ggrid, 256, 0, stream>>>(xa_hi, xa_lo, w1t_hi, w1t_lo, hbuf, N);
    agg_kernel<0><<<agrid, 256, 0, stream>>>(hbuf, rp, cv, dinv, b1,
                                             xa_hi, xa_lo, nullptr, nullptr, nullptr, N);
    // layer 2: GEMM (pre-split a) -> bf16 h -> agg + fused head (atomic partials)
    gemm_split_kernel<<<ggrid, 256, 0, stream>>>(xa_hi, xa_lo, w2t_hi, w2t_lo, hbuf, N);
    agg_kernel<1><<<agrid, 256, 0, stream>>>(hbuf, rp, cv, dinv, b2,
                                             nullptr, nullptr, Wf, bf, out, N);
}

// Round 15
// 576.021 us; speedup vs baseline: 1.0104x; 1.0104x over previous
//
#include <hip/hip_runtime.h>
#include <hip/hip_bf16.h>
#include <cstdint>

#define IN_C 256

typedef __attribute__((ext_vector_type(8))) short bf16x8;
typedef __attribute__((ext_vector_type(8))) short s16x8;
typedef __attribute__((ext_vector_type(4))) short s16x4;
typedef __attribute__((ext_vector_type(8))) unsigned short u16x8;
typedef __attribute__((ext_vector_type(4))) float f32x4;

#define FIXED_SCALE 33554432.0f          // 2^25
#define FIXED_INV   (1.0f / 33554432.0f)
#define DEG_MASK    ((1ULL << 40) - 1)

// ---- bf16 split helpers (RNE) ----
__device__ inline unsigned short f2bf(float f) {
    union { float f; unsigned int u; } v; v.f = f;
    unsigned int r = (v.u + 0x7fffu + ((v.u >> 16) & 1u)) >> 16;
    return (unsigned short)r;
}
__device__ inline float bf2f(unsigned short b) {
    union { unsigned int u; float f; } v; v.u = ((unsigned int)b) << 16;
    return v.f;
}
// returns .x = hi bf16 bits, .y = lo bf16 bits
__device__ inline short2 split1(float f) {
    unsigned short hb = f2bf(f);
    unsigned short lb = f2bf(f - bf2f(hb));
    return make_short2((short)hb, (short)lb);
}

// ---------------- per-edge: ONE packed u64 atomic = deg (fixed-point) + cnt + rank ----
__global__ void deg_count_kernel(const int* __restrict__ ei, const float* __restrict__ w,
                                 unsigned long long* __restrict__ packed,
                                 unsigned short* __restrict__ rank, int E) {
    int e = blockIdx.x * blockDim.x + threadIdx.x;
    if (e >= E) return;
    int dst = ei[E + e];
    unsigned int fx = __float2uint_rn(w[e] * FIXED_SCALE);
    unsigned long long inc = (1ULL << 40) | (unsigned long long)fx;
    unsigned long long old = atomicAdd(&packed[dst], inc);
    rank[e] = (unsigned short)(old >> 40);
}

// ---------------- exclusive scan of cnt -> row_ptr (3-kernel); scan1 also dinv ----------------
#define SCAN_B 256
__global__ void scan1_kernel(const unsigned long long* __restrict__ packed,
                             int* __restrict__ rp, int* __restrict__ bsum,
                             float* __restrict__ dinv, int N) {
    __shared__ int s[SCAN_B];
    int tid = threadIdx.x;
    int i = blockIdx.x * SCAN_B + tid;
    int v = 0;
    if (i < N) {
        unsigned long long pk = packed[i];
        v = (int)(pk >> 40);
        float deg = (float)(pk & DEG_MASK) * FIXED_INV;
        dinv[i] = rsqrtf(deg + 1.0f);         // +1 = self loop weight
    }
    s[tid] = v;
    __syncthreads();
    for (int off = 1; off < SCAN_B; off <<= 1) {
        int t = (tid >= off) ? s[tid - off] : 0;
        __syncthreads();
        s[tid] += t;
        __syncthreads();
    }
    if (i < N) rp[i] = s[tid] - v;            // exclusive within block
    if (tid == SCAN_B - 1) bsum[blockIdx.x] = s[tid];
}

__global__ void scan2_kernel(int* __restrict__ bsum, int* __restrict__ boff, int nb) {
    __shared__ int s[SCAN_B];
    int tid = threadIdx.x;
    int v = (tid < nb) ? bsum[tid] : 0;
    s[tid] = v;
    __syncthreads();
    for (int off = 1; off < SCAN_B; off <<= 1) {
        int t = (tid >= off) ? s[tid - off] : 0;
        __syncthreads();
        s[tid] += t;
        __syncthreads();
    }
    if (tid < nb) boff[tid] = s[tid] - v;     // exclusive across blocks
}

__global__ void scan3_kernel(int* __restrict__ rp, const int* __restrict__ boff,
                             int N, int E) {
    int i = blockIdx.x * blockDim.x + threadIdx.x;
    if (i < N) rp[i] = rp[i] + boff[i >> 8];
    if (i == 0) rp[N] = E;
}

// ---------------- CSR fill, ATOMIC-FREE: pos = rp[dst] + rank[e] ----------------
__global__ void fill_kernel(const int* __restrict__ ei, const float* __restrict__ w,
                            const float* __restrict__ dinv,
                            const int* __restrict__ rp,
                            const unsigned short* __restrict__ rank,
                            int2* __restrict__ cv, int E) {
    int e = blockIdx.x * blockDim.x + threadIdx.x;
    if (e >= E) return;
    int src = ei[e];
    int dst = ei[E + e];
    int pos = rp[dst] + (int)rank[e];
    // defensive clamp: never allow a wild store outside [0,E)
    if ((unsigned)pos < (unsigned)E) {
        float v = dinv[src] * w[e] * dinv[dst];
        cv[pos] = make_int2(src, __float_as_int(v));
    }
}

// ---------------- prep: W1/W2 transpose+split AND x split, one launch ----------------
__global__ void prep_kernel(const float* __restrict__ W1, const float* __restrict__ W2,
                            const float* __restrict__ x,
                            unsigned short* __restrict__ w1t_hi, unsigned short* __restrict__ w1t_lo,
                            unsigned short* __restrict__ w2t_hi, unsigned short* __restrict__ w2t_lo,
                            unsigned short* __restrict__ x_hi, unsigned short* __restrict__ x_lo,
                            int nx4) {
    int b = blockIdx.x;
    if (b < 512) {
        const float* W = (b < 256) ? W1 : W2;
        unsigned short* hi = (b < 256) ? w1t_hi : w2t_hi;
        unsigned short* lo = (b < 256) ? w1t_lo : w2t_lo;
        int n = b & 255;       // col of W
        int k = threadIdx.x;   // row of W
        float v = W[(size_t)k * 256 + n];
        short2 s = split1(v);
        hi[(size_t)n * 256 + k] = (unsigned short)s.x;
        lo[(size_t)n * 256 + k] = (unsigned short)s.y;
    } else {
        int i = (b - 512) * 256 + threadIdx.x;   // float4 index
        if (i < nx4) {
            float4 v = ((const float4*)x)[i];
            short2 sx = split1(v.x), sy = split1(v.y), sz = split1(v.z), sw = split1(v.w);
            s16x4 hv, lv;
            hv.x = sx.x; hv.y = sy.x; hv.z = sz.x; hv.w = sw.x;
            lv.x = sx.y; lv.y = sy.y; lv.z = sz.y; lv.w = sw.y;
            *(s16x4*)(x_hi + (size_t)i * 4) = hv;
            *(s16x4*)(x_lo + (size_t)i * 4) = lv;
        }
    }
}

// ---------------- split-bf16 MFMA GEMM ----------------
// C16[N][256] (plain bf16) = A[N][256] @ B[256][256] in ~fp32 precision via 3x bf16 MFMA.
__global__ __launch_bounds__(256) void gemm_split_kernel(
    const unsigned short* __restrict__ Ahg,
    const unsigned short* __restrict__ Alg,
    const unsigned short* __restrict__ Bth,   // Wt_hi [n][k]
    const unsigned short* __restrict__ Btl,   // Wt_lo [n][k]
    unsigned short* __restrict__ C16, int Nrows)
{
    __shared__ __align__(16) short Ah[128 * 64];
    __shared__ __align__(16) short Al[128 * 64];
    __shared__ __align__(16) short Bh[128 * 64];
    __shared__ __align__(16) short Bl[128 * 64];

    const int t    = threadIdx.x;
    const int lane = t & 63;
    const int w    = t >> 6;
    const int r0   = blockIdx.x * 128;
    const int cb0  = blockIdx.y * 128;
    const int fr   = lane & 15;          // frag row (A: m-row / B: n-col)
    const int fk   = (lane >> 4) * 8;    // frag k offset
    const int wm   = w * 32;             // wave's m-band

    f32x4 acc[2][8] = {};

    for (int k0 = 0; k0 < 256; k0 += 64) {
        __syncthreads();
        // ---- stage B tile [128 n][64 k] (hi+lo) ----
#pragma unroll
        for (int c = 0; c < 4; ++c) {
            int i = c * 256 + t;
            int row = i >> 3, seg = i & 7;
            size_t g = (size_t)(cb0 + row) * 256 + k0 + seg * 8;
            *(s16x8*)&Bh[row * 64 + seg * 8] = *(const s16x8*)(Bth + g);
            *(s16x8*)&Bl[row * 64 + seg * 8] = *(const s16x8*)(Btl + g);
        }
        // ---- stage A tile [128 m][64 k] (hi+lo) ----
#pragma unroll
        for (int c = 0; c < 4; ++c) {
            int i = c * 256 + t;
            int row = i >> 3, seg = i & 7;
            int gr = r0 + row; if (gr > Nrows - 1) gr = Nrows - 1;
            size_t g = (size_t)gr * 256 + k0 + seg * 8;
            *(s16x8*)&Ah[row * 64 + seg * 8] = *(const s16x8*)(Ahg + g);
            *(s16x8*)&Al[row * 64 + seg * 8] = *(const s16x8*)(Alg + g);
        }
        __syncthreads();
        // ---- compute: 2 k-steps of 32, 2m x 8n frags, 3 MFMA each ----
#pragma unroll
        for (int ks = 0; ks < 2; ++ks) {
            int ko = ks * 32 + fk;
            bf16x8 ah[2], al[2];
#pragma unroll
            for (int mi = 0; mi < 2; ++mi) {
                ah[mi] = *(const bf16x8*)&Ah[(wm + mi * 16 + fr) * 64 + ko];
                al[mi] = *(const bf16x8*)&Al[(wm + mi * 16 + fr) * 64 + ko];
            }
#pragma unroll
            for (int n = 0; n < 8; ++n) {
                bf16x8 bh = *(const bf16x8*)&Bh[(n * 16 + fr) * 64 + ko];
                bf16x8 bl = *(const bf16x8*)&Bl[(n * 16 + fr) * 64 + ko];
#pragma unroll
                for (int mi = 0; mi < 2; ++mi) {
                    acc[mi][n] = __builtin_amdgcn_mfma_f32_16x16x32_bf16(ah[mi], bh, acc[mi][n], 0, 0, 0);
                    acc[mi][n] = __builtin_amdgcn_mfma_f32_16x16x32_bf16(ah[mi], bl, acc[mi][n], 0, 0, 0);
                    acc[mi][n] = __builtin_amdgcn_mfma_f32_16x16x32_bf16(al[mi], bh, acc[mi][n], 0, 0, 0);
                }
            }
        }
    }
    // ---- epilogue: C/D layout col=lane&15, row=(lane>>4)*4+reg; store plain bf16 ----
    const int rb = (lane >> 4) * 4;
#pragma unroll
    for (int mi = 0; mi < 2; ++mi) {
#pragma unroll
        for (int n = 0; n < 8; ++n) {
            int col = cb0 + n * 16 + fr;
#pragma unroll
            for (int r = 0; r < 4; ++r) {
                int row = r0 + wm + mi * 16 + rb + r;
                if (row < Nrows) C16[(size_t)row * 256 + col] = f2bf(acc[mi][n][r]);
            }
        }
    }
}

// ---- 8-channel bf16 FMA helper ----
__device__ inline void fma8(float* acc, u16x8 g, float v) {
#pragma unroll
    for (int c = 0; c < 8; ++c) acc[c] = fmaf(v, bf2f(g[c]), acc[c]);
}

// ---------------- XCD-PINNED CHANNEL-PHASED CSR aggregation ----------------
// phase = blockIdx.x & 7: hardware dispatches block i to XCD i%8 (empirical
// round-robin, m157-swizzle model), so ALL blocks of phase p run on XCD p.
// Per-XCD gather working set = N*64B = 3.2MB < 4MB private L2 -> gathers hit
// L2 after compulsory fill. (R14's blockIdx.y phasing kept all phases
// co-resident per XCD -> no isolation, and 64B slices cost x1.6 line waste.)
// Quarter-wave (4 lanes x 16B) per dst; unroll-8 edge loop keeps 8 dwordx4
// gathers in flight per lane (proven shape; 8B loads 6.7x slower — R6/R7).
// MODE 0: relu + bf16 hi/lo split.  MODE 1: relu + head partial -> atomicAdd.
template<int MODE>
__global__ __launch_bounds__(256) void agg_kernel(const unsigned short* __restrict__ h16,
                                                  const int* __restrict__ rp,
                                                  const int2* __restrict__ cv,
                                                  const float* __restrict__ dinv,
                                                  const float* __restrict__ bias,
                                                  unsigned short* __restrict__ out_hi,
                                                  unsigned short* __restrict__ out_lo,
                                                  const float* __restrict__ Wf,
                                                  const float* __restrict__ bf,
                                                  float* __restrict__ out,
                                                  int N) {
    int phase = blockIdx.x & 7;              // -> XCD (round-robin dispatch)
    int dg    = blockIdx.x >> 3;
    int q  = threadIdx.x >> 2;               // quarter id 0..63
    int ql = threadIdx.x & 3;                // lane within quarter
    int d  = dg * 64 + q;
    if (d >= N) return;
    int co = phase * 32 + ql * 8;            // this lane's channel offset

    float di = dinv[d];
    float selfm = di * di;                   // self loop, weight 1
    u16x8 sv = *(const u16x8*)(h16 + (size_t)d * 256 + co);
    float acc[8];
#pragma unroll
    for (int c = 0; c < 8; ++c) acc[c] = selfm * bf2f(sv[c]);

    int s = rp[d], e = rp[d + 1];
    for (int j = s; j < e; j += 8) {
        int   ec[8]; float ev[8];
#pragma unroll
        for (int i = 0; i < 8; ++i) {
            int idx = j + i;
            int2 c = cv[idx < e ? idx : e - 1];
            ec[i] = c.x;
            ev[i] = (idx < e) ? __int_as_float(c.y) : 0.0f;
        }
        u16x8 g0 = *(const u16x8*)(h16 + (size_t)ec[0] * 256 + co);
        u16x8 g1 = *(const u16x8*)(h16 + (size_t)ec[1] * 256 + co);
        u16x8 g2 = *(const u16x8*)(h16 + (size_t)ec[2] * 256 + co);
        u16x8 g3 = *(const u16x8*)(h16 + (size_t)ec[3] * 256 + co);
        u16x8 g4 = *(const u16x8*)(h16 + (size_t)ec[4] * 256 + co);
        u16x8 g5 = *(const u16x8*)(h16 + (size_t)ec[5] * 256 + co);
        u16x8 g6 = *(const u16x8*)(h16 + (size_t)ec[6] * 256 + co);
        u16x8 g7 = *(const u16x8*)(h16 + (size_t)ec[7] * 256 + co);
        fma8(acc, g0, ev[0]);
        fma8(acc, g1, ev[1]);
        fma8(acc, g2, ev[2]);
        fma8(acc, g3, ev[3]);
        fma8(acc, g4, ev[4]);
        fma8(acc, g5, ev[5]);
        fma8(acc, g6, ev[6]);
        fma8(acc, g7, ev[7]);
    }

    float4 b0 = *(const float4*)(bias + co);
    float4 b1 = *(const float4*)(bias + co + 4);
    acc[0] = fmaxf(acc[0] + b0.x, 0.0f);
    acc[1] = fmaxf(acc[1] + b0.y, 0.0f);
    acc[2] = fmaxf(acc[2] + b0.z, 0.0f);
    acc[3] = fmaxf(acc[3] + b0.w, 0.0f);
    acc[4] = fmaxf(acc[4] + b1.x, 0.0f);
    acc[5] = fmaxf(acc[5] + b1.y, 0.0f);
    acc[6] = fmaxf(acc[6] + b1.z, 0.0f);
    acc[7] = fmaxf(acc[7] + b1.w, 0.0f);

    if constexpr (MODE == 0) {
        u16x8 hi, lo;
#pragma unroll
        for (int c = 0; c < 8; ++c) {
            hi[c] = f2bf(acc[c]);
            lo[c] = f2bf(acc[c] - bf2f(hi[c]));
        }
        *(u16x8*)(out_hi + (size_t)d * 256 + co) = hi;
        *(u16x8*)(out_lo + (size_t)d * 256 + co) = lo;
    } else {
        float4 wf0 = *(const float4*)(Wf + co);
        float4 wf1 = *(const float4*)(Wf + co + 4);
        float sdot = acc[0] * wf0.x + acc[1] * wf0.y + acc[2] * wf0.z + acc[3] * wf0.w
                   + acc[4] * wf1.x + acc[5] * wf1.y + acc[6] * wf1.z + acc[7] * wf1.w;
        sdot += __shfl_xor(sdot, 1);
        sdot += __shfl_xor(sdot, 2);
        if (ql == 0) {
            if (phase == 0) sdot += bf[0];        // bias added exactly once
            atomicAdd(&out[d], sdot);
        }
    }
}

// ---------------- host launch ----------------
extern "C" void kernel_launch(void* const* d_in, const int* in_sizes, int n_in,
                              void* d_out, int out_size, void* d_ws, size_t ws_size,
                              hipStream_t stream) {
    const float* x  = (const float*)d_in[0];
    const int*   ei = (const int*)d_in[1];
    const float* w  = (const float*)d_in[2];
    const float* W1 = (const float*)d_in[3];
    const float* b1 = (const float*)d_in[4];
    const float* W2 = (const float*)d_in[5];
    const float* b2 = (const float*)d_in[6];
    const float* Wf = (const float*)d_in[7];
    const float* bf = (const float*)d_in[8];
    float* out = (float*)d_out;

    const int N = in_sizes[0] / IN_C;
    const int E = in_sizes[2];

    // workspace layout (256B aligned)
    auto align256 = [](size_t v) { return (v + 255) & ~(size_t)255; };
    char* p = (char*)d_ws;
    unsigned long long* packed = (unsigned long long*)p; p += align256((size_t)N * 8);
    float* dinv   = (float*)p; p += align256((size_t)N * 4);
    int*   rp     = (int*)p;   p += align256(((size_t)N + 1) * 4);
    int*   bsum   = (int*)p;   p += align256(SCAN_B * 4);
    int*   boff   = (int*)p;   p += align256(SCAN_B * 4);
    unsigned short* rank = (unsigned short*)p; p += align256((size_t)E * 2);
    int2*  cv     = (int2*)p;  p += align256((size_t)E * 8);
    unsigned short* w1t_hi = (unsigned short*)p; p += align256((size_t)256 * 256 * 2);
    unsigned short* w1t_lo = (unsigned short*)p; p += align256((size_t)256 * 256 * 2);
    unsigned short* w2t_hi = (unsigned short*)p; p += align256((size_t)256 * 256 * 2);
    unsigned short* w2t_lo = (unsigned short*)p; p += align256((size_t)256 * 256 * 2);
    unsigned short* hbuf  = (unsigned short*)p; p += align256((size_t)N * 256 * 2);  // plain bf16 GEMM out
    // xa_hi/xa_lo: x pre-split (read by GEMM1), then REUSED by agg1 as a_hi/a_lo
    unsigned short* xa_hi = (unsigned short*)p; p += align256((size_t)N * 256 * 2);
    unsigned short* xa_lo = (unsigned short*)p; p += align256((size_t)N * 256 * 2);
    (void)ws_size; (void)n_in; (void)out_size;

    const int nb_edges = (E + 255) / 256;
    const int nb_nodes = (N + 255) / 256;
    const int nb_scan  = (N + SCAN_B - 1) / SCAN_B;
    const int nx4      = N * 256 / 4;

    // zero packed deg/cnt accumulators + output (head accumulates via atomics)
    hipMemsetAsync(packed, 0, (size_t)N * 8, stream);
    hipMemsetAsync(out, 0, (size_t)N * 4, stream);

    // graph normalization + CSR build (single atomic pass; fill is atomic-free)
    deg_count_kernel<<<nb_edges, 256, 0, stream>>>(ei, w, packed, rank, E);
    scan1_kernel<<<nb_scan, SCAN_B, 0, stream>>>(packed, rp, bsum, dinv, N);
    scan2_kernel<<<1, SCAN_B, 0, stream>>>(bsum, boff, nb_scan);
    scan3_kernel<<<nb_nodes, 256, 0, stream>>>(rp, boff, N, E);
    fill_kernel<<<nb_edges, 256, 0, stream>>>(ei, w, dinv, rp, rank, cv, E);

    // prep: W1/W2 transpose+split and x split, one launch
    prep_kernel<<<512 + (nx4 + 255) / 256, 256, 0, stream>>>(
        W1, W2, x, w1t_hi, w1t_lo, w2t_hi, w2t_lo, xa_hi, xa_lo, nx4);

    dim3 ggrid((N + 127) / 128, 2);
    const int nb_agg = ((N + 63) / 64) * 8;   // x = dgroup*8 + phase (phase -> XCD)

    // layer 1: GEMM (pre-split x) -> bf16 h -> agg (writes bf16 hi/lo into xa_*)
    gemm_split_kernel<<<ggrid, 256, 0, stream>>>(xa_hi, xa_lo, w1t_hi, w1t_lo, hbuf, N);
    agg_kernel<0><<<nb_agg, 256, 0, stream>>>(hbuf, rp, cv, dinv, b1,
                                              xa_hi, xa_lo, nullptr, nullptr, nullptr, N);
    // layer 2: GEMM (pre-split a) -> bf16 h -> agg + fused head (atomic partials)
    gemm_split_kernel<<<ggrid, 256, 0, stream>>>(xa_hi, xa_lo, w2t_hi, w2t_lo, hbuf, N);
    agg_kernel<1><<<nb_agg, 256, 0, stream>>>(hbuf, rp, cv, dinv, b2,
                                              nullptr, nullptr, Wf, bf, out, N);
}

// Round 16
// 471.371 us; speedup vs baseline: 1.2347x; 1.2220x over previous
//
#include <hip/hip_runtime.h>
#include <hip/hip_bf16.h>
#include <cstdint>

#define IN_C 256

typedef __attribute__((ext_vector_type(8))) short bf16x8;
typedef __attribute__((ext_vector_type(8))) short s16x8;
typedef __attribute__((ext_vector_type(4))) short s16x4;
typedef __attribute__((ext_vector_type(8))) unsigned short u16x8;
typedef __attribute__((ext_vector_type(4))) float f32x4;

#define FIXED_SCALE 33554432.0f          // 2^25
#define FIXED_INV   (1.0f / 33554432.0f)
#define DEG_MASK    ((1ULL << 40) - 1)

// ---- bf16 split helpers (RNE) ----
__device__ inline unsigned short f2bf(float f) {
    union { float f; unsigned int u; } v; v.f = f;
    unsigned int r = (v.u + 0x7fffu + ((v.u >> 16) & 1u)) >> 16;
    return (unsigned short)r;
}
__device__ inline float bf2f(unsigned short b) {
    union { unsigned int u; float f; } v; v.u = ((unsigned int)b) << 16;
    return v.f;
}
// returns .x = hi bf16 bits, .y = lo bf16 bits
__device__ inline short2 split1(float f) {
    unsigned short hb = f2bf(f);
    unsigned short lb = f2bf(f - bf2f(hb));
    return make_short2((short)hb, (short)lb);
}

// ---------------- per-edge: ONE packed u64 atomic = deg (fixed-point) + cnt + rank ----
__global__ void deg_count_kernel(const int* __restrict__ ei, const float* __restrict__ w,
                                 unsigned long long* __restrict__ packed,
                                 unsigned short* __restrict__ rank, int E) {
    int e = blockIdx.x * blockDim.x + threadIdx.x;
    if (e >= E) return;
    int dst = ei[E + e];
    unsigned int fx = __float2uint_rn(w[e] * FIXED_SCALE);
    unsigned long long inc = (1ULL << 40) | (unsigned long long)fx;
    unsigned long long old = atomicAdd(&packed[dst], inc);
    rank[e] = (unsigned short)(old >> 40);
}

// ---------------- exclusive scan of cnt -> row_ptr (3-kernel); scan1 also dinv ----------------
#define SCAN_B 256
__global__ void scan1_kernel(const unsigned long long* __restrict__ packed,
                             int* __restrict__ rp, int* __restrict__ bsum,
                             float* __restrict__ dinv, int N) {
    __shared__ int s[SCAN_B];
    int tid = threadIdx.x;
    int i = blockIdx.x * SCAN_B + tid;
    int v = 0;
    if (i < N) {
        unsigned long long pk = packed[i];
        v = (int)(pk >> 40);
        float deg = (float)(pk & DEG_MASK) * FIXED_INV;
        dinv[i] = rsqrtf(deg + 1.0f);         // +1 = self loop weight
    }
    s[tid] = v;
    __syncthreads();
    for (int off = 1; off < SCAN_B; off <<= 1) {
        int t = (tid >= off) ? s[tid - off] : 0;
        __syncthreads();
        s[tid] += t;
        __syncthreads();
    }
    if (i < N) rp[i] = s[tid] - v;            // exclusive within block
    if (tid == SCAN_B - 1) bsum[blockIdx.x] = s[tid];
}

__global__ void scan2_kernel(int* __restrict__ bsum, int* __restrict__ boff, int nb) {
    __shared__ int s[SCAN_B];
    int tid = threadIdx.x;
    int v = (tid < nb) ? bsum[tid] : 0;
    s[tid] = v;
    __syncthreads();
    for (int off = 1; off < SCAN_B; off <<= 1) {
        int t = (tid >= off) ? s[tid - off] : 0;
        __syncthreads();
        s[tid] += t;
        __syncthreads();
    }
    if (tid < nb) boff[tid] = s[tid] - v;     // exclusive across blocks
}

__global__ void scan3_kernel(int* __restrict__ rp, const int* __restrict__ boff,
                             int N, int E) {
    int i = blockIdx.x * blockDim.x + threadIdx.x;
    if (i < N) rp[i] = rp[i] + boff[i >> 8];
    if (i == 0) rp[N] = E;
}

// ---------------- CSR fill, ATOMIC-FREE: pos = rp[dst] + rank[e] ----------------
__global__ void fill_kernel(const int* __restrict__ ei, const float* __restrict__ w,
                            const float* __restrict__ dinv,
                            const int* __restrict__ rp,
                            const unsigned short* __restrict__ rank,
                            int2* __restrict__ cv, int E) {
    int e = blockIdx.x * blockDim.x + threadIdx.x;
    if (e >= E) return;
    int src = ei[e];
    int dst = ei[E + e];
    int pos = rp[dst] + (int)rank[e];
    // defensive clamp: never allow a wild store outside [0,E)
    if ((unsigned)pos < (unsigned)E) {
        float v = dinv[src] * w[e] * dinv[dst];
        cv[pos] = make_int2(src, __float_as_int(v));
    }
}

// ---------------- prep: W1/W2 transpose+split AND x split, one launch ----------------
__global__ void prep_kernel(const float* __restrict__ W1, const float* __restrict__ W2,
                            const float* __restrict__ x,
                            unsigned short* __restrict__ w1t_hi, unsigned short* __restrict__ w1t_lo,
                            unsigned short* __restrict__ w2t_hi, unsigned short* __restrict__ w2t_lo,
                            unsigned short* __restrict__ x_hi, unsigned short* __restrict__ x_lo,
                            int nx4) {
    int b = blockIdx.x;
    if (b < 512) {
        const float* W = (b < 256) ? W1 : W2;
        unsigned short* hi = (b < 256) ? w1t_hi : w2t_hi;
        unsigned short* lo = (b < 256) ? w1t_lo : w2t_lo;
        int n = b & 255;       // col of W
        int k = threadIdx.x;   // row of W
        float v = W[(size_t)k * 256 + n];
        short2 s = split1(v);
        hi[(size_t)n * 256 + k] = (unsigned short)s.x;
        lo[(size_t)n * 256 + k] = (unsigned short)s.y;
    } else {
        int i = (b - 512) * 256 + threadIdx.x;   // float4 index
        if (i < nx4) {
            float4 v = ((const float4*)x)[i];
            short2 sx = split1(v.x), sy = split1(v.y), sz = split1(v.z), sw = split1(v.w);
            s16x4 hv, lv;
            hv.x = sx.x; hv.y = sy.x; hv.z = sz.x; hv.w = sw.x;
            lv.x = sx.y; lv.y = sy.y; lv.z = sz.y; lv.w = sw.y;
            *(s16x4*)(x_hi + (size_t)i * 4) = hv;
            *(s16x4*)(x_lo + (size_t)i * 4) = lv;
        }
    }
}

// ---------------- split-bf16 MFMA GEMM ----------------
// C16[N][256] (plain bf16) = A[N][256] @ B[256][256] in ~fp32 precision via 3x bf16 MFMA.
__global__ __launch_bounds__(256) void gemm_split_kernel(
    const unsigned short* __restrict__ Ahg,
    const unsigned short* __restrict__ Alg,
    const unsigned short* __restrict__ Bth,   // Wt_hi [n][k]
    const unsigned short* __restrict__ Btl,   // Wt_lo [n][k]
    unsigned short* __restrict__ C16, int Nrows)
{
    __shared__ __align__(16) short Ah[128 * 64];
    __shared__ __align__(16) short Al[128 * 64];
    __shared__ __align__(16) short Bh[128 * 64];
    __shared__ __align__(16) short Bl[128 * 64];

    const int t    = threadIdx.x;
    const int lane = t & 63;
    const int w    = t >> 6;
    const int r0   = blockIdx.x * 128;
    const int cb0  = blockIdx.y * 128;
    const int fr   = lane & 15;          // frag row (A: m-row / B: n-col)
    const int fk   = (lane >> 4) * 8;    // frag k offset
    const int wm   = w * 32;             // wave's m-band

    f32x4 acc[2][8] = {};

    for (int k0 = 0; k0 < 256; k0 += 64) {
        __syncthreads();
        // ---- stage B tile [128 n][64 k] (hi+lo) ----
#pragma unroll
        for (int c = 0; c < 4; ++c) {
            int i = c * 256 + t;
            int row = i >> 3, seg = i & 7;
            size_t g = (size_t)(cb0 + row) * 256 + k0 + seg * 8;
            *(s16x8*)&Bh[row * 64 + seg * 8] = *(const s16x8*)(Bth + g);
            *(s16x8*)&Bl[row * 64 + seg * 8] = *(const s16x8*)(Btl + g);
        }
        // ---- stage A tile [128 m][64 k] (hi+lo) ----
#pragma unroll
        for (int c = 0; c < 4; ++c) {
            int i = c * 256 + t;
            int row = i >> 3, seg = i & 7;
            int gr = r0 + row; if (gr > Nrows - 1) gr = Nrows - 1;
            size_t g = (size_t)gr * 256 + k0 + seg * 8;
            *(s16x8*)&Ah[row * 64 + seg * 8] = *(const s16x8*)(Ahg + g);
            *(s16x8*)&Al[row * 64 + seg * 8] = *(const s16x8*)(Alg + g);
        }
        __syncthreads();
        // ---- compute: 2 k-steps of 32, 2m x 8n frags, 3 MFMA each ----
#pragma unroll
        for (int ks = 0; ks < 2; ++ks) {
            int ko = ks * 32 + fk;
            bf16x8 ah[2], al[2];
#pragma unroll
            for (int mi = 0; mi < 2; ++mi) {
                ah[mi] = *(const bf16x8*)&Ah[(wm + mi * 16 + fr) * 64 + ko];
                al[mi] = *(const bf16x8*)&Al[(wm + mi * 16 + fr) * 64 + ko];
            }
#pragma unroll
            for (int n = 0; n < 8; ++n) {
                bf16x8 bh = *(const bf16x8*)&Bh[(n * 16 + fr) * 64 + ko];
                bf16x8 bl = *(const bf16x8*)&Bl[(n * 16 + fr) * 64 + ko];
#pragma unroll
                for (int mi = 0; mi < 2; ++mi) {
                    acc[mi][n] = __builtin_amdgcn_mfma_f32_16x16x32_bf16(ah[mi], bh, acc[mi][n], 0, 0, 0);
                    acc[mi][n] = __builtin_amdgcn_mfma_f32_16x16x32_bf16(ah[mi], bl, acc[mi][n], 0, 0, 0);
                    acc[mi][n] = __builtin_amdgcn_mfma_f32_16x16x32_bf16(al[mi], bh, acc[mi][n], 0, 0, 0);
                }
            }
        }
    }
    // ---- epilogue: C/D layout col=lane&15, row=(lane>>4)*4+reg; store plain bf16 ----
    const int rb = (lane >> 4) * 4;
#pragma unroll
    for (int mi = 0; mi < 2; ++mi) {
#pragma unroll
        for (int n = 0; n < 8; ++n) {
            int col = cb0 + n * 16 + fr;
#pragma unroll
            for (int r = 0; r < 4; ++r) {
                int row = r0 + wm + mi * 16 + rb + r;
                if (row < Nrows) C16[(size_t)row * 256 + col] = f2bf(acc[mi][n][r]);
            }
        }
    }
}

// ---- 8-channel bf16 FMA helper ----
__device__ inline void fma8(float* acc, u16x8 g, float v) {
#pragma unroll
    for (int c = 0; c < 8; ++c) acc[c] = fmaf(v, bf2f(g[c]), acc[c]);
}

// ---------------- CSR aggregation + self loop + bias + relu (+optional fused head) ----
// R13-proven structure (112us, FETCH 361MB): bf16-h gather, HALF-WAVE-per-edge
// keeps the 16B/lane global_load_dwordx4 shape (8B loads collapse to ~2 in
// flight, 6.7x slower — R6/R7). One wave per dst; lane l handles 8 channels
// [8*(l&31),+8) of edge j+2t+(l>>5); 16-edge main loop = 8 dwordx4 in flight,
// 8-edge mid tier, then 2/1-edge tail. cv = packed (col,val).
// Channel-phasing REFUTED (R14 blockIdx.y: +60% FETCH line-waste; R15
// XCD-pinning: no isolation) — full-row gathers use every fetched byte.
// MODE 0: relu + bf16 hi/lo split.  MODE 1: relu + fused head (wave-reduce).
template<int MODE>
__global__ __launch_bounds__(256) void agg_kernel(const unsigned short* __restrict__ h16,
                                                  const int* __restrict__ rp,
                                                  const int2* __restrict__ cv,
                                                  const float* __restrict__ dinv,
                                                  const float* __restrict__ bias,
                                                  unsigned short* __restrict__ out_hi,
                                                  unsigned short* __restrict__ out_lo,
                                                  const float* __restrict__ Wf,
                                                  const float* __restrict__ bf,
                                                  float* __restrict__ out,
                                                  int N) {
    int d    = blockIdx.x * 4 + (threadIdx.x >> 6);
    int lane = threadIdx.x & 63;
    if (d >= N) return;
    int half = lane >> 5;
    int co   = (lane & 31) * 8;          // this lane's channel offset

    float di = dinv[d];
    float selfm = half ? 0.0f : di * di;           // count self loop once
    u16x8 sv = *(const u16x8*)(h16 + (size_t)d * 256 + co);
    float acc[8];
#pragma unroll
    for (int c = 0; c < 8; ++c) acc[c] = selfm * bf2f(sv[c]);

    int s = rp[d], e = rp[d + 1];
    int j = s;
    for (; j + 16 <= e; j += 16) {
        int   ec[8]; float ev[8];
#pragma unroll
        for (int t2 = 0; t2 < 8; ++t2) {
            int2 ca = cv[j + 2 * t2], cb = cv[j + 2 * t2 + 1];
            ec[t2] = half ? cb.x : ca.x;
            ev[t2] = __int_as_float(half ? cb.y : ca.y);
        }
        u16x8 g0 = *(const u16x8*)(h16 + (size_t)ec[0] * 256 + co);
        u16x8 g1 = *(const u16x8*)(h16 + (size_t)ec[1] * 256 + co);
        u16x8 g2 = *(const u16x8*)(h16 + (size_t)ec[2] * 256 + co);
        u16x8 g3 = *(const u16x8*)(h16 + (size_t)ec[3] * 256 + co);
        u16x8 g4 = *(const u16x8*)(h16 + (size_t)ec[4] * 256 + co);
        u16x8 g5 = *(const u16x8*)(h16 + (size_t)ec[5] * 256 + co);
        u16x8 g6 = *(const u16x8*)(h16 + (size_t)ec[6] * 256 + co);
        u16x8 g7 = *(const u16x8*)(h16 + (size_t)ec[7] * 256 + co);
        fma8(acc, g0, ev[0]);
        fma8(acc, g1, ev[1]);
        fma8(acc, g2, ev[2]);
        fma8(acc, g3, ev[3]);
        fma8(acc, g4, ev[4]);
        fma8(acc, g5, ev[5]);
        fma8(acc, g6, ev[6]);
        fma8(acc, g7, ev[7]);
    }
    for (; j + 8 <= e; j += 8) {
        int   ec[4]; float ev[4];
#pragma unroll
        for (int t2 = 0; t2 < 4; ++t2) {
            int2 ca = cv[j + 2 * t2], cb = cv[j + 2 * t2 + 1];
            ec[t2] = half ? cb.x : ca.x;
            ev[t2] = __int_as_float(half ? cb.y : ca.y);
        }
        u16x8 g0 = *(const u16x8*)(h16 + (size_t)ec[0] * 256 + co);
        u16x8 g1 = *(const u16x8*)(h16 + (size_t)ec[1] * 256 + co);
        u16x8 g2 = *(const u16x8*)(h16 + (size_t)ec[2] * 256 + co);
        u16x8 g3 = *(const u16x8*)(h16 + (size_t)ec[3] * 256 + co);
        fma8(acc, g0, ev[0]);
        fma8(acc, g1, ev[1]);
        fma8(acc, g2, ev[2]);
        fma8(acc, g3, ev[3]);
    }
    for (; j + 2 <= e; j += 2) {
        int2 ca = cv[j], cb = cv[j + 1];
        int   ee = half ? cb.x : ca.x;
        float vv = __int_as_float(half ? cb.y : ca.y);
        u16x8 g = *(const u16x8*)(h16 + (size_t)ee * 256 + co);
        fma8(acc, g, vv);
    }
    if (j < e) {                                    // single leftover edge
        int2 ca = cv[j];
        int   ee = ca.x;
        float vv = half ? 0.0f : __int_as_float(ca.y);
        u16x8 g = *(const u16x8*)(h16 + (size_t)ee * 256 + co);
        fma8(acc, g, vv);
    }

    // combine halves: both halves end with the full per-channel sums
#pragma unroll
    for (int c = 0; c < 8; ++c) acc[c] += __shfl_xor(acc[c], 32);

    float4 b0 = *(const float4*)(bias + co);
    float4 b1 = *(const float4*)(bias + co + 4);
    acc[0] = fmaxf(acc[0] + b0.x, 0.0f);
    acc[1] = fmaxf(acc[1] + b0.y, 0.0f);
    acc[2] = fmaxf(acc[2] + b0.z, 0.0f);
    acc[3] = fmaxf(acc[3] + b0.w, 0.0f);
    acc[4] = fmaxf(acc[4] + b1.x, 0.0f);
    acc[5] = fmaxf(acc[5] + b1.y, 0.0f);
    acc[6] = fmaxf(acc[6] + b1.z, 0.0f);
    acc[7] = fmaxf(acc[7] + b1.w, 0.0f);

    if constexpr (MODE == 0) {
        u16x8 hi;
#pragma unroll
        for (int c = 0; c < 8; ++c) hi[c] = f2bf(acc[c]);
        if (half == 0) {
            *(u16x8*)(out_hi + (size_t)d * 256 + co) = hi;
        } else {
            u16x8 lo;
#pragma unroll
            for (int c = 0; c < 8; ++c) lo[c] = f2bf(acc[c] - bf2f(hi[c]));
            *(u16x8*)(out_lo + (size_t)d * 256 + co) = lo;
        }
    } else {
        float4 wf0 = *(const float4*)(Wf + co);
        float4 wf1 = *(const float4*)(Wf + co + 4);
        float sdot = acc[0] * wf0.x + acc[1] * wf0.y + acc[2] * wf0.z + acc[3] * wf0.w
                   + acc[4] * wf1.x + acc[5] * wf1.y + acc[6] * wf1.z + acc[7] * wf1.w;
        for (int o = 16; o; o >>= 1) sdot += __shfl_down(sdot, o);   // per-half reduce
        if (lane == 0) out[d] = sdot + bf[0];
    }
}

// ---------------- host launch ----------------
extern "C" void kernel_launch(void* const* d_in, const int* in_sizes, int n_in,
                              void* d_out, int out_size, void* d_ws, size_t ws_size,
                              hipStream_t stream) {
    const float* x  = (const float*)d_in[0];
    const int*   ei = (const int*)d_in[1];
    const float* w  = (const float*)d_in[2];
    const float* W1 = (const float*)d_in[3];
    const float* b1 = (const float*)d_in[4];
    const float* W2 = (const float*)d_in[5];
    const float* b2 = (const float*)d_in[6];
    const float* Wf = (const float*)d_in[7];
    const float* bf = (const float*)d_in[8];
    float* out = (float*)d_out;

    const int N = in_sizes[0] / IN_C;
    const int E = in_sizes[2];

    // workspace layout (256B aligned)
    auto align256 = [](size_t v) { return (v + 255) & ~(size_t)255; };
    char* p = (char*)d_ws;
    unsigned long long* packed = (unsigned long long*)p; p += align256((size_t)N * 8);
    float* dinv   = (float*)p; p += align256((size_t)N * 4);
    int*   rp     = (int*)p;   p += align256(((size_t)N + 1) * 4);
    int*   bsum   = (int*)p;   p += align256(SCAN_B * 4);
    int*   boff   = (int*)p;   p += align256(SCAN_B * 4);
    unsigned short* rank = (unsigned short*)p; p += align256((size_t)E * 2);
    int2*  cv     = (int2*)p;  p += align256((size_t)E * 8);
    unsigned short* w1t_hi = (unsigned short*)p; p += align256((size_t)256 * 256 * 2);
    unsigned short* w1t_lo = (unsigned short*)p; p += align256((size_t)256 * 256 * 2);
    unsigned short* w2t_hi = (unsigned short*)p; p += align256((size_t)256 * 256 * 2);
    unsigned short* w2t_lo = (unsigned short*)p; p += align256((size_t)256 * 256 * 2);
    unsigned short* hbuf  = (unsigned short*)p; p += align256((size_t)N * 256 * 2);  // plain bf16 GEMM out
    // xa_hi/xa_lo: x pre-split (read by GEMM1), then REUSED by agg1 as a_hi/a_lo
    unsigned short* xa_hi = (unsigned short*)p; p += align256((size_t)N * 256 * 2);
    unsigned short* xa_lo = (unsigned short*)p; p += align256((size_t)N * 256 * 2);
    (void)ws_size; (void)n_in; (void)out_size;

    const int nb_edges = (E + 255) / 256;
    const int nb_nodes = (N + 255) / 256;
    const int nb_scan  = (N + SCAN_B - 1) / SCAN_B;
    const int nx4      = N * 256 / 4;

    // zero packed deg/cnt accumulators
    hipMemsetAsync(packed, 0, (size_t)N * 8, stream);

    // graph normalization + CSR build (single atomic pass; fill is atomic-free)
    deg_count_kernel<<<nb_edges, 256, 0, stream>>>(ei, w, packed, rank, E);
    scan1_kernel<<<nb_scan, SCAN_B, 0, stream>>>(packed, rp, bsum, dinv, N);
    scan2_kernel<<<1, SCAN_B, 0, stream>>>(bsum, boff, nb_scan);
    scan3_kernel<<<nb_nodes, 256, 0, stream>>>(rp, boff, N, E);
    fill_kernel<<<nb_edges, 256, 0, stream>>>(ei, w, dinv, rp, rank, cv, E);

    // prep: W1/W2 transpose+split and x split, one launch
    prep_kernel<<<512 + (nx4 + 255) / 256, 256, 0, stream>>>(
        W1, W2, x, w1t_hi, w1t_lo, w2t_hi, w2t_lo, xa_hi, xa_lo, nx4);

    dim3 ggrid((N + 127) / 128, 2);
    const int nb_agg = (N + 3) / 4;

    // layer 1: GEMM (pre-split x) -> bf16 h -> agg (writes bf16 hi/lo into xa_*)
    gemm_split_kernel<<<ggrid, 256, 0, stream>>>(xa_hi, xa_lo, w1t_hi, w1t_lo, hbuf, N);
    agg_kernel<0><<<nb_agg, 256, 0, stream>>>(hbuf, rp, cv, dinv, b1,
                                              xa_hi, xa_lo, nullptr, nullptr, nullptr, N);
    // layer 2: GEMM (pre-split a) -> bf16 h -> agg + fused head
    gemm_split_kernel<<<ggrid, 256, 0, stream>>>(xa_hi, xa_lo, w2t_hi, w2t_lo, hbuf, N);
    agg_kernel<1><<<nb_agg, 256, 0, stream>>>(hbuf, rp, cv, dinv, b2,
                                              nullptr, nullptr, Wf, bf, out, N);
}

// Round 17
// 454.936 us; speedup vs baseline: 1.2793x; 1.0361x over previous
//
#include <hip/hip_runtime.h>
#include <hip/hip_bf16.h>
#include <cstdint>

#define IN_C 256

typedef __attribute__((ext_vector_type(8))) short bf16x8;
typedef __attribute__((ext_vector_type(8))) short s16x8;
typedef __attribute__((ext_vector_type(4))) short s16x4;
typedef __attribute__((ext_vector_type(8))) unsigned short u16x8;
typedef __attribute__((ext_vector_type(4))) float f32x4;

#define FIXED_SCALE 33554432.0f          // 2^25
#define FIXED_INV   (1.0f / 33554432.0f)
#define DEG_MASK    ((1ULL << 40) - 1)

// ---- bf16 split helpers (RNE) ----
__device__ inline unsigned short f2bf(float f) {
    union { float f; unsigned int u; } v; v.f = f;
    unsigned int r = (v.u + 0x7fffu + ((v.u >> 16) & 1u)) >> 16;
    return (unsigned short)r;
}
__device__ inline float bf2f(unsigned short b) {
    union { unsigned int u; float f; } v; v.u = ((unsigned int)b) << 16;
    return v.f;
}
// returns .x = hi bf16 bits, .y = lo bf16 bits
__device__ inline short2 split1(float f) {
    unsigned short hb = f2bf(f);
    unsigned short lb = f2bf(f - bf2f(hb));
    return make_short2((short)hb, (short)lb);
}

// ---------------- per-edge: ONE packed u64 atomic = deg (fixed-point) + cnt + rank ----
__global__ void deg_count_kernel(const int* __restrict__ ei, const float* __restrict__ w,
                                 unsigned long long* __restrict__ packed,
                                 unsigned short* __restrict__ rank, int E) {
    int e = blockIdx.x * blockDim.x + threadIdx.x;
    if (e >= E) return;
    int dst = ei[E + e];
    unsigned int fx = __float2uint_rn(w[e] * FIXED_SCALE);
    unsigned long long inc = (1ULL << 40) | (unsigned long long)fx;
    unsigned long long old = atomicAdd(&packed[dst], inc);
    rank[e] = (unsigned short)(old >> 40);
}

// ---------------- exclusive scan of cnt -> row_ptr (3-kernel); scan1 also dinv ----------------
#define SCAN_B 256
__global__ void scan1_kernel(const unsigned long long* __restrict__ packed,
                             int* __restrict__ rp, int* __restrict__ bsum,
                             float* __restrict__ dinv, int N) {
    __shared__ int s[SCAN_B];
    int tid = threadIdx.x;
    int i = blockIdx.x * SCAN_B + tid;
    int v = 0;
    if (i < N) {
        unsigned long long pk = packed[i];
        v = (int)(pk >> 40);
        float deg = (float)(pk & DEG_MASK) * FIXED_INV;
        dinv[i] = rsqrtf(deg + 1.0f);         // +1 = self loop weight
    }
    s[tid] = v;
    __syncthreads();
    for (int off = 1; off < SCAN_B; off <<= 1) {
        int t = (tid >= off) ? s[tid - off] : 0;
        __syncthreads();
        s[tid] += t;
        __syncthreads();
    }
    if (i < N) rp[i] = s[tid] - v;            // exclusive within block
    if (tid == SCAN_B - 1) bsum[blockIdx.x] = s[tid];
}

__global__ void scan2_kernel(int* __restrict__ bsum, int* __restrict__ boff, int nb) {
    __shared__ int s[SCAN_B];
    int tid = threadIdx.x;
    int v = (tid < nb) ? bsum[tid] : 0;
    s[tid] = v;
    __syncthreads();
    for (int off = 1; off < SCAN_B; off <<= 1) {
        int t = (tid >= off) ? s[tid - off] : 0;
        __syncthreads();
        s[tid] += t;
        __syncthreads();
    }
    if (tid < nb) boff[tid] = s[tid] - v;     // exclusive across blocks
}

__global__ void scan3_kernel(int* __restrict__ rp, const int* __restrict__ boff,
                             int N, int E) {
    int i = blockIdx.x * blockDim.x + threadIdx.x;
    if (i < N) rp[i] = rp[i] + boff[i >> 8];
    if (i == 0) rp[N] = E;
}

// ---------------- CSR fill, ATOMIC-FREE: pos = rp[dst] + rank[e] ----------------
__global__ void fill_kernel(const int* __restrict__ ei, const float* __restrict__ w,
                            const float* __restrict__ dinv,
                            const int* __restrict__ rp,
                            const unsigned short* __restrict__ rank,
                            int2* __restrict__ cv, int E) {
    int e = blockIdx.x * blockDim.x + threadIdx.x;
    if (e >= E) return;
    int src = ei[e];
    int dst = ei[E + e];
    int pos = rp[dst] + (int)rank[e];
    // defensive clamp: never allow a wild store outside [0,E)
    if ((unsigned)pos < (unsigned)E) {
        float v = dinv[src] * w[e] * dinv[dst];
        cv[pos] = make_int2(src, __float_as_int(v));
    }
}

// ---------------- prep: W1/W2 transpose+split AND x split, one launch ----------------
__global__ void prep_kernel(const float* __restrict__ W1, const float* __restrict__ W2,
                            const float* __restrict__ x,
                            unsigned short* __restrict__ w1t_hi, unsigned short* __restrict__ w1t_lo,
                            unsigned short* __restrict__ w2t_hi, unsigned short* __restrict__ w2t_lo,
                            unsigned short* __restrict__ x_hi, unsigned short* __restrict__ x_lo,
                            int nx4) {
    int b = blockIdx.x;
    if (b < 512) {
        const float* W = (b < 256) ? W1 : W2;
        unsigned short* hi = (b < 256) ? w1t_hi : w2t_hi;
        unsigned short* lo = (b < 256) ? w1t_lo : w2t_lo;
        int n = b & 255;       // col of W
        int k = threadIdx.x;   // row of W
        float v = W[(size_t)k * 256 + n];
        short2 s = split1(v);
        hi[(size_t)n * 256 + k] = (unsigned short)s.x;
        lo[(size_t)n * 256 + k] = (unsigned short)s.y;
    } else {
        int i = (b - 512) * 256 + threadIdx.x;   // float4 index
        if (i < nx4) {
            float4 v = ((const float4*)x)[i];
            short2 sx = split1(v.x), sy = split1(v.y), sz = split1(v.z), sw = split1(v.w);
            s16x4 hv, lv;
            hv.x = sx.x; hv.y = sy.x; hv.z = sz.x; hv.w = sw.x;
            lv.x = sx.y; lv.y = sy.y; lv.z = sz.y; lv.w = sw.y;
            *(s16x4*)(x_hi + (size_t)i * 4) = hv;
            *(s16x4*)(x_lo + (size_t)i * 4) = lv;
        }
    }
}

// ---------------- split-bf16 MFMA GEMM ----------------
// C16[N][256] (plain bf16) = A[N][256] @ B[256][256] via bf16 MFMA.
// B always hi/lo split. ASPLIT: A also split (3 MFMA/frag, ~fp32 A);
// !ASPLIT: A plain bf16 (2 MFMA/frag — the dropped al*bh term IS A's bf16
// rounding error; used for layer 2 where a1 is stored plain bf16).
template<bool ASPLIT>
__global__ __launch_bounds__(256) void gemm_split_kernel(
    const unsigned short* __restrict__ Ahg,
    const unsigned short* __restrict__ Alg,
    const unsigned short* __restrict__ Bth,   // Wt_hi [n][k]
    const unsigned short* __restrict__ Btl,   // Wt_lo [n][k]
    unsigned short* __restrict__ C16, int Nrows)
{
    __shared__ __align__(16) short Ah[128 * 64];
    __shared__ __align__(16) short Al[ASPLIT ? 128 * 64 : 8];
    __shared__ __align__(16) short Bh[128 * 64];
    __shared__ __align__(16) short Bl[128 * 64];

    const int t    = threadIdx.x;
    const int lane = t & 63;
    const int w    = t >> 6;
    const int r0   = blockIdx.x * 128;
    const int cb0  = blockIdx.y * 128;
    const int fr   = lane & 15;          // frag row (A: m-row / B: n-col)
    const int fk   = (lane >> 4) * 8;    // frag k offset
    const int wm   = w * 32;             // wave's m-band

    f32x4 acc[2][8] = {};

    for (int k0 = 0; k0 < 256; k0 += 64) {
        __syncthreads();
        // ---- stage B tile [128 n][64 k] (hi+lo) ----
#pragma unroll
        for (int c = 0; c < 4; ++c) {
            int i = c * 256 + t;
            int row = i >> 3, seg = i & 7;
            size_t g = (size_t)(cb0 + row) * 256 + k0 + seg * 8;
            *(s16x8*)&Bh[row * 64 + seg * 8] = *(const s16x8*)(Bth + g);
            *(s16x8*)&Bl[row * 64 + seg * 8] = *(const s16x8*)(Btl + g);
        }
        // ---- stage A tile [128 m][64 k] ----
#pragma unroll
        for (int c = 0; c < 4; ++c) {
            int i = c * 256 + t;
            int row = i >> 3, seg = i & 7;
            int gr = r0 + row; if (gr > Nrows - 1) gr = Nrows - 1;
            size_t g = (size_t)gr * 256 + k0 + seg * 8;
            *(s16x8*)&Ah[row * 64 + seg * 8] = *(const s16x8*)(Ahg + g);
            if constexpr (ASPLIT)
                *(s16x8*)&Al[row * 64 + seg * 8] = *(const s16x8*)(Alg + g);
        }
        __syncthreads();
        // ---- compute: 2 k-steps of 32, 2m x 8n frags ----
#pragma unroll
        for (int ks = 0; ks < 2; ++ks) {
            int ko = ks * 32 + fk;
            bf16x8 ah[2], al[2];
#pragma unroll
            for (int mi = 0; mi < 2; ++mi) {
                ah[mi] = *(const bf16x8*)&Ah[(wm + mi * 16 + fr) * 64 + ko];
                if constexpr (ASPLIT)
                    al[mi] = *(const bf16x8*)&Al[(wm + mi * 16 + fr) * 64 + ko];
            }
#pragma unroll
            for (int n = 0; n < 8; ++n) {
                bf16x8 bh = *(const bf16x8*)&Bh[(n * 16 + fr) * 64 + ko];
                bf16x8 bl = *(const bf16x8*)&Bl[(n * 16 + fr) * 64 + ko];
#pragma unroll
                for (int mi = 0; mi < 2; ++mi) {
                    acc[mi][n] = __builtin_amdgcn_mfma_f32_16x16x32_bf16(ah[mi], bh, acc[mi][n], 0, 0, 0);
                    acc[mi][n] = __builtin_amdgcn_mfma_f32_16x16x32_bf16(ah[mi], bl, acc[mi][n], 0, 0, 0);
                    if constexpr (ASPLIT)
                        acc[mi][n] = __builtin_amdgcn_mfma_f32_16x16x32_bf16(al[mi], bh, acc[mi][n], 0, 0, 0);
                }
            }
        }
    }
    // ---- epilogue: C/D layout col=lane&15, row=(lane>>4)*4+reg; store plain bf16 ----
    const int rb = (lane >> 4) * 4;
#pragma unroll
    for (int mi = 0; mi < 2; ++mi) {
#pragma unroll
        for (int n = 0; n < 8; ++n) {
            int col = cb0 + n * 16 + fr;
#pragma unroll
            for (int r = 0; r < 4; ++r) {
                int row = r0 + wm + mi * 16 + rb + r;
                if (row < Nrows) C16[(size_t)row * 256 + col] = f2bf(acc[mi][n][r]);
            }
        }
    }
}

// ---- 8-channel bf16 FMA helper ----
__device__ inline void fma8(float* acc, u16x8 g, float v) {
#pragma unroll
    for (int c = 0; c < 8; ++c) acc[c] = fmaf(v, bf2f(g[c]), acc[c]);
}

// ---------------- CSR aggregation + self loop + bias + relu (+optional fused head) ----
// R13-proven structure (112us, FETCH 361MB): bf16-h gather, HALF-WAVE-per-edge
// keeps the 16B/lane global_load_dwordx4 shape (8B loads collapse to ~2 in
// flight, 6.7x slower — R6/R7). One wave per dst; lane l handles 8 channels
// [8*(l&31),+8) of edge j+2t+(l>>5); 16-edge main loop = 8 dwordx4 in flight,
// 8-edge mid tier, then 2/1-edge tail. cv = packed (col,val).
// Channel-phasing REFUTED (R14/R15) — full-row gathers use every fetched byte.
// MODE 0: relu + PLAIN bf16 out (half0 stores; lo dropped — one dyadic absmax
// step, GEMM2 compensates with 2-MFMA plain-A path).
// MODE 1: relu + fused head (wave-reduce).
template<int MODE>
__global__ __launch_bounds__(256) void agg_kernel(const unsigned short* __restrict__ h16,
                                                  const int* __restrict__ rp,
                                                  const int2* __restrict__ cv,
                                                  const float* __restrict__ dinv,
                                                  const float* __restrict__ bias,
                                                  unsigned short* __restrict__ out_hi,
                                                  const float* __restrict__ Wf,
                                                  const float* __restrict__ bf,
                                                  float* __restrict__ out,
                                                  int N) {
    int d    = blockIdx.x * 4 + (threadIdx.x >> 6);
    int lane = threadIdx.x & 63;
    if (d >= N) return;
    int half = lane >> 5;
    int co   = (lane & 31) * 8;          // this lane's channel offset

    float di = dinv[d];
    float selfm = half ? 0.0f : di * di;           // count self loop once
    u16x8 sv = *(const u16x8*)(h16 + (size_t)d * 256 + co);
    float acc[8];
#pragma unroll
    for (int c = 0; c < 8; ++c) acc[c] = selfm * bf2f(sv[c]);

    int s = rp[d], e = rp[d + 1];
    int j = s;
    for (; j + 16 <= e; j += 16) {
        int   ec[8]; float ev[8];
#pragma unroll
        for (int t2 = 0; t2 < 8; ++t2) {
            int2 ca = cv[j + 2 * t2], cb = cv[j + 2 * t2 + 1];
            ec[t2] = half ? cb.x : ca.x;
            ev[t2] = __int_as_float(half ? cb.y : ca.y);
        }
        u16x8 g0 = *(const u16x8*)(h16 + (size_t)ec[0] * 256 + co);
        u16x8 g1 = *(const u16x8*)(h16 + (size_t)ec[1] * 256 + co);
        u16x8 g2 = *(const u16x8*)(h16 + (size_t)ec[2] * 256 + co);
        u16x8 g3 = *(const u16x8*)(h16 + (size_t)ec[3] * 256 + co);
        u16x8 g4 = *(const u16x8*)(h16 + (size_t)ec[4] * 256 + co);
        u16x8 g5 = *(const u16x8*)(h16 + (size_t)ec[5] * 256 + co);
        u16x8 g6 = *(const u16x8*)(h16 + (size_t)ec[6] * 256 + co);
        u16x8 g7 = *(const u16x8*)(h16 + (size_t)ec[7] * 256 + co);
        fma8(acc, g0, ev[0]);
        fma8(acc, g1, ev[1]);
        fma8(acc, g2, ev[2]);
        fma8(acc, g3, ev[3]);
        fma8(acc, g4, ev[4]);
        fma8(acc, g5, ev[5]);
        fma8(acc, g6, ev[6]);
        fma8(acc, g7, ev[7]);
    }
    for (; j + 8 <= e; j += 8) {
        int   ec[4]; float ev[4];
#pragma unroll
        for (int t2 = 0; t2 < 4; ++t2) {
            int2 ca = cv[j + 2 * t2], cb = cv[j + 2 * t2 + 1];
            ec[t2] = half ? cb.x : ca.x;
            ev[t2] = __int_as_float(half ? cb.y : ca.y);
        }
        u16x8 g0 = *(const u16x8*)(h16 + (size_t)ec[0] * 256 + co);
        u16x8 g1 = *(const u16x8*)(h16 + (size_t)ec[1] * 256 + co);
        u16x8 g2 = *(const u16x8*)(h16 + (size_t)ec[2] * 256 + co);
        u16x8 g3 = *(const u16x8*)(h16 + (size_t)ec[3] * 256 + co);
        fma8(acc, g0, ev[0]);
        fma8(acc, g1, ev[1]);
        fma8(acc, g2, ev[2]);
        fma8(acc, g3, ev[3]);
    }
    for (; j + 2 <= e; j += 2) {
        int2 ca = cv[j], cb = cv[j + 1];
        int   ee = half ? cb.x : ca.x;
        float vv = __int_as_float(half ? cb.y : ca.y);
        u16x8 g = *(const u16x8*)(h16 + (size_t)ee * 256 + co);
        fma8(acc, g, vv);
    }
    if (j < e) {                                    // single leftover edge
        int2 ca = cv[j];
        int   ee = ca.x;
        float vv = half ? 0.0f : __int_as_float(ca.y);
        u16x8 g = *(const u16x8*)(h16 + (size_t)ee * 256 + co);
        fma8(acc, g, vv);
    }

    // combine halves: both halves end with the full per-channel sums
#pragma unroll
    for (int c = 0; c < 8; ++c) acc[c] += __shfl_xor(acc[c], 32);

    float4 b0 = *(const float4*)(bias + co);
    float4 b1 = *(const float4*)(bias + co + 4);
    acc[0] = fmaxf(acc[0] + b0.x, 0.0f);
    acc[1] = fmaxf(acc[1] + b0.y, 0.0f);
    acc[2] = fmaxf(acc[2] + b0.z, 0.0f);
    acc[3] = fmaxf(acc[3] + b0.w, 0.0f);
    acc[4] = fmaxf(acc[4] + b1.x, 0.0f);
    acc[5] = fmaxf(acc[5] + b1.y, 0.0f);
    acc[6] = fmaxf(acc[6] + b1.z, 0.0f);
    acc[7] = fmaxf(acc[7] + b1.w, 0.0f);

    if constexpr (MODE == 0) {
        if (half == 0) {
            u16x8 hi;
#pragma unroll
            for (int c = 0; c < 8; ++c) hi[c] = f2bf(acc[c]);
            *(u16x8*)(out_hi + (size_t)d * 256 + co) = hi;
        }
    } else {
        float4 wf0 = *(const float4*)(Wf + co);
        float4 wf1 = *(const float4*)(Wf + co + 4);
        float sdot = acc[0] * wf0.x + acc[1] * wf0.y + acc[2] * wf0.z + acc[3] * wf0.w
                   + acc[4] * wf1.x + acc[5] * wf1.y + acc[6] * wf1.z + acc[7] * wf1.w;
        for (int o = 16; o; o >>= 1) sdot += __shfl_down(sdot, o);   // per-half reduce
        if (lane == 0) out[d] = sdot + bf[0];
    }
}

// ---------------- host launch ----------------
extern "C" void kernel_launch(void* const* d_in, const int* in_sizes, int n_in,
                              void* d_out, int out_size, void* d_ws, size_t ws_size,
                              hipStream_t stream) {
    const float* x  = (const float*)d_in[0];
    const int*   ei = (const int*)d_in[1];
    const float* w  = (const float*)d_in[2];
    const float* W1 = (const float*)d_in[3];
    const float* b1 = (const float*)d_in[4];
    const float* W2 = (const float*)d_in[5];
    const float* b2 = (const float*)d_in[6];
    const float* Wf = (const float*)d_in[7];
    const float* bf = (const float*)d_in[8];
    float* out = (float*)d_out;

    const int N = in_sizes[0] / IN_C;
    const int E = in_sizes[2];

    // workspace layout (256B aligned)
    auto align256 = [](size_t v) { return (v + 255) & ~(size_t)255; };
    char* p = (char*)d_ws;
    unsigned long long* packed = (unsigned long long*)p; p += align256((size_t)N * 8);
    float* dinv   = (float*)p; p += align256((size_t)N * 4);
    int*   rp     = (int*)p;   p += align256(((size_t)N + 1) * 4);
    int*   bsum   = (int*)p;   p += align256(SCAN_B * 4);
    int*   boff   = (int*)p;   p += align256(SCAN_B * 4);
    unsigned short* rank = (unsigned short*)p; p += align256((size_t)E * 2);
    int2*  cv     = (int2*)p;  p += align256((size_t)E * 8);
    unsigned short* w1t_hi = (unsigned short*)p; p += align256((size_t)256 * 256 * 2);
    unsigned short* w1t_lo = (unsigned short*)p; p += align256((size_t)256 * 256 * 2);
    unsigned short* w2t_hi = (unsigned short*)p; p += align256((size_t)256 * 256 * 2);
    unsigned short* w2t_lo = (unsigned short*)p; p += align256((size_t)256 * 256 * 2);
    unsigned short* hbuf  = (unsigned short*)p; p += align256((size_t)N * 256 * 2);  // plain bf16 GEMM out
    // xa_hi/xa_lo: x pre-split (read by GEMM1); xa_hi then REUSED as a1 (plain bf16)
    unsigned short* xa_hi = (unsigned short*)p; p += align256((size_t)N * 256 * 2);
    unsigned short* xa_lo = (unsigned short*)p; p += align256((size_t)N * 256 * 2);
    (void)ws_size; (void)n_in; (void)out_size;

    const int nb_edges = (E + 255) / 256;
    const int nb_nodes = (N + 255) / 256;
    const int nb_scan  = (N + SCAN_B - 1) / SCAN_B;
    const int nx4      = N * 256 / 4;

    // zero packed deg/cnt accumulators
    hipMemsetAsync(packed, 0, (size_t)N * 8, stream);

    // graph normalization + CSR build (single atomic pass; fill is atomic-free)
    deg_count_kernel<<<nb_edges, 256, 0, stream>>>(ei, w, packed, rank, E);
    scan1_kernel<<<nb_scan, SCAN_B, 0, stream>>>(packed, rp, bsum, dinv, N);
    scan2_kernel<<<1, SCAN_B, 0, stream>>>(bsum, boff, nb_scan);
    scan3_kernel<<<nb_nodes, 256, 0, stream>>>(rp, boff, N, E);
    fill_kernel<<<nb_edges, 256, 0, stream>>>(ei, w, dinv, rp, rank, cv, E);

    // prep: W1/W2 transpose+split and x split, one launch
    prep_kernel<<<512 + (nx4 + 255) / 256, 256, 0, stream>>>(
        W1, W2, x, w1t_hi, w1t_lo, w2t_hi, w2t_lo, xa_hi, xa_lo, nx4);

    dim3 ggrid((N + 127) / 128, 2);
    const int nb_agg = (N + 3) / 4;

    // layer 1: GEMM (split x, 3-MFMA) -> bf16 h -> agg1 (plain bf16 a1 into xa_hi)
    gemm_split_kernel<true><<<ggrid, 256, 0, stream>>>(xa_hi, xa_lo,
                                                       w1t_hi, w1t_lo, hbuf, N);
    agg_kernel<0><<<nb_agg, 256, 0, stream>>>(hbuf, rp, cv, dinv, b1,
                                              xa_hi, nullptr, nullptr, nullptr, N);
    // layer 2: GEMM (plain bf16 a1, 2-MFMA) -> bf16 h -> agg2 + fused head
    gemm_split_kernel<false><<<ggrid, 256, 0, stream>>>(xa_hi, nullptr,
                                                        w2t_hi, w2t_lo, hbuf, N);
    agg_kernel<1><<<nb_agg, 256, 0, stream>>>(hbuf, rp, cv, dinv, b2,
                                              nullptr, Wf, bf, out, N);
}